// Round 6
// baseline (523.048 us; speedup 1.0000x reference)
//
#include <hip/hip_runtime.h>
#include <stdint.h>

// Problem constants (fixed shapes)
#define DIMX 4096
#define NH   32
#define NKV  8
#define HD   128
#define SEQ  2048
#define QKVD 6144   // 4096 q + 1024 k + 1024 v

typedef _Float16 h16;
typedef __attribute__((ext_vector_type(8))) _Float16 h16x8;
typedef __attribute__((ext_vector_type(4))) _Float16 h16x4;
typedef __attribute__((ext_vector_type(4))) float   f32x4;

__device__ __forceinline__ void gload_lds16(const void* g, void* l) {
  __builtin_amdgcn_global_load_lds(
      (const __attribute__((address_space(1))) void*)g,
      (__attribute__((address_space(3))) void*)l, 16, 0, 0);
}

// ---- 16-lane reductions on the VALU via DPP reversal butterflies (no LDS pipe) ----
template <int CTRL>
__device__ __forceinline__ float dpp_mv(float x) {
  int y = __builtin_amdgcn_mov_dpp(__builtin_bit_cast(int, x), CTRL, 0xF, 0xF, true);
  return __builtin_bit_cast(float, y);
}
__device__ __forceinline__ float red16_max(float x) {
  x = fmaxf(x, dpp_mv<0xB1>(x));   // rev2: quad_perm(1,0,3,2)
  x = fmaxf(x, dpp_mv<0x1B>(x));   // rev4: quad_perm(3,2,1,0)
  x = fmaxf(x, dpp_mv<0x141>(x));  // rev8: row_half_mirror
  x = fmaxf(x, dpp_mv<0x140>(x));  // rev16: row_mirror
  return x;
}
__device__ __forceinline__ float red16_sum(float x) {
  x += dpp_mv<0xB1>(x);
  x += dpp_mv<0x1B>(x);
  x += dpp_mv<0x141>(x);
  x += dpp_mv<0x140>(x);
  return x;
}

// ---------- fused dequant (all 4 weights) + x cast, vectorized; flag computed per block ----------
__device__ __forceinline__ void dq_unit(const void* __restrict__ w, const float* __restrict__ sc,
                                        h16* __restrict__ out, int u, int flag) {
  uint32_t b4;
  if (flag) {
    const int4 t = *(const int4*)((const int*)w + 4 * u);
    b4 = (uint32_t)(t.x & 0xFF) | ((uint32_t)(t.y & 0xFF) << 8) |
         ((uint32_t)(t.z & 0xFF) << 16) | ((uint32_t)(t.w & 0xFF) << 24);
  } else {
    b4 = ((const uint32_t*)w)[u];
  }
  int r = u >> 4;
  int p = (u & 15) * 4;
  float shi = sc[2 * r], slo = sc[2 * r + 1];
  h16x4 hi, lo;
#pragma unroll
  for (int j = 0; j < 4; ++j) {
    int by = (int)((b4 >> (8 * j)) & 0xFF);
    int hn = (by << 24) >> 28;
    int ln = (by << 28) >> 28;
    hi[j] = (h16)((float)hn * shi);
    lo[j] = (h16)((float)ln * slo);
  }
  *(h16x4*)(out + (r << 7) + p)      = hi;
  *(h16x4*)(out + (r << 7) + 64 + p) = lo;
}

#define U_WQ 2097152
#define U_WK 524288
#define U_WV 524288
#define U_WO 2097152

__global__ __launch_bounds__(256) void prep_all(
    const void* __restrict__ wq, const float* __restrict__ sq,
    const void* __restrict__ wk, const float* __restrict__ sk,
    const void* __restrict__ wv, const float* __restrict__ sv,
    const void* __restrict__ wo, const float* __restrict__ so,
    const float4* __restrict__ x,
    h16* __restrict__ Wqkv, h16* __restrict__ Wo, h16x4* __restrict__ xb) {
  __shared__ int sfl;
  if (threadIdx.x == 0) {
    int ok = 1;
    const int* wi = (const int*)wq;
    for (int i = 0; i < 64; ++i) {
      int v = wi[i];
      if (v < -128 || v > 127) ok = 0;
    }
    sfl = ok;   // 1: ints were widened to int32; 0: raw int8 bytes
  }
  __syncthreads();
  const int fl = sfl;
  int u = blockIdx.x * 256 + threadIdx.x;
  if (u < U_WQ) { dq_unit(wq, sq, Wqkv, u, fl); return; }
  u -= U_WQ;
  if (u < U_WK) { dq_unit(wk, sk, Wqkv + 16777216, u, fl); return; }
  u -= U_WK;
  if (u < U_WV) { dq_unit(wv, sv, Wqkv + 20971520, u, fl); return; }
  u -= U_WV;
  if (u < U_WO) { dq_unit(wo, so, Wo, u, fl); return; }
  u -= U_WO;
  {
    float4 v = x[u];
    h16x4 o;
    o.x = (h16)v.x; o.y = (h16)v.y; o.z = (h16)v.z; o.w = (h16)v.w;
    xb[u] = o;
  }
}

// ---------- GEMM: C[M,N] = A[M,K] @ B[N,K]^T, fp16 in, OutT out ----------
// 128x128 tile, BK=64 (XOR chunk swizzle: row stride 128B, chunk cs holds global
// chunk cs^(row&7) -> conflict-free b128 reads), half the barriers of BK=32.
template <typename OutT>
__global__ __launch_bounds__(256) void gemm_bt(
    const h16* __restrict__ A, const h16* __restrict__ B,
    OutT* __restrict__ C, int M, int N, int K) {
  __shared__ __attribute__((aligned(16))) h16 As[128 * 64];
  __shared__ __attribute__((aligned(16))) h16 Bs[128 * 64];
  const int tid  = threadIdx.x;
  const int wv   = tid >> 6, lane = tid & 63;
  const int wr   = wv >> 1,  wc   = wv & 1;
  const int quad = lane >> 4, l15 = lane & 15;
  const int m0 = blockIdx.y * 128, n0 = blockIdx.x * 128;

  f32x4 acc[4][4];
#pragma unroll
  for (int i = 0; i < 4; ++i)
#pragma unroll
    for (int j = 0; j < 4; ++j) acc[i][j] = (f32x4){0.f, 0.f, 0.f, 0.f};

  const h16* Ab = A + (size_t)m0 * K;
  const h16* Bb = B + (size_t)n0 * K;

  for (int k0 = 0; k0 < K; k0 += 64) {
    __syncthreads();
#pragma unroll
    for (int i = 0; i < 4; ++i) {
      int c = i * 256 + tid;           // 1024 slots per matrix
      int row = c >> 3, cs = c & 7;
      int g = cs ^ (row & 7);          // global chunk held at this slot
      gload_lds16(Ab + (size_t)row * K + k0 + g * 8, (char*)As + c * 16);
      gload_lds16(Bb + (size_t)row * K + k0 + g * 8, (char*)Bs + c * 16);
    }
    __syncthreads();

#pragma unroll
    for (int ks = 0; ks < 2; ++ks) {
      h16x8 af[4], bfr[4];
#pragma unroll
      for (int mt = 0; mt < 4; ++mt) {
        int row = wr * 64 + mt * 16 + l15;
        af[mt] = *(const h16x8*)&As[row * 64 + (((ks * 4 + quad) ^ (row & 7)) * 8)];
      }
#pragma unroll
      for (int nt = 0; nt < 4; ++nt) {
        int row = wc * 64 + nt * 16 + l15;
        bfr[nt] = *(const h16x8*)&Bs[row * 64 + (((ks * 4 + quad) ^ (row & 7)) * 8)];
      }
#pragma unroll
      for (int mt = 0; mt < 4; ++mt)
#pragma unroll
        for (int nt = 0; nt < 4; ++nt)
          acc[mt][nt] = __builtin_amdgcn_mfma_f32_16x16x32_f16(af[mt], bfr[nt], acc[mt][nt], 0, 0, 0);
    }
  }
#pragma unroll
  for (int mt = 0; mt < 4; ++mt)
#pragma unroll
    for (int nt = 0; nt < 4; ++nt)
#pragma unroll
      for (int r = 0; r < 4; ++r) {
        int row = m0 + wr * 64 + mt * 16 + quad * 4 + r;
        int col = n0 + wc * 64 + nt * 16 + l15;
        C[(size_t)row * N + col] = (OutT)acc[mt][nt][r];
      }
}

// ---------- fused RoPE (blocks 0..5119) + V transpose (blocks 5120..5631) ----------
__global__ __launch_bounds__(256) void rope_vtrans(
    h16* __restrict__ qkv, const float* __restrict__ cosb, const float* __restrict__ sinb,
    h16* __restrict__ vt) {
  __shared__ h16 T[64 * 66];
  int b = blockIdx.x;
  if (b < 5120) {
    int idx = b * 256 + threadIdx.x;
    int d4 = (idx & 15) * 4;
    int t  = idx >> 4;
    int hh = t % 40;
    int s  = t / 40;
    int base = (hh < 32) ? (s * QKVD + hh * 128)
                         : (s * QKVD + 4096 + (hh - 32) * 128);
    h16x4 a = *(const h16x4*)(qkv + base + d4);
    h16x4 bb = *(const h16x4*)(qkv + base + 64 + d4);
    float4 c  = *(const float4*)(cosb + s * 64 + d4);
    float4 sn = *(const float4*)(sinb + s * 64 + d4);
    h16x4 oa, ob;
    oa.x = (h16)((float)a.x * c.x - (float)bb.x * sn.x);
    oa.y = (h16)((float)a.y * c.y - (float)bb.y * sn.y);
    oa.z = (h16)((float)a.z * c.z - (float)bb.z * sn.z);
    oa.w = (h16)((float)a.w * c.w - (float)bb.w * sn.w);
    ob.x = (h16)((float)bb.x * c.x + (float)a.x * sn.x);
    ob.y = (h16)((float)bb.y * c.y + (float)a.y * sn.y);
    ob.z = (h16)((float)bb.z * c.z + (float)a.z * sn.z);
    ob.w = (h16)((float)bb.w * c.w + (float)a.w * sn.w);
    *(h16x4*)(qkv + base + d4)      = oa;
    *(h16x4*)(qkv + base + 64 + d4) = ob;
  } else {
    int i = b - 5120;                 // [0, 512)
    int kv = i >> 6;
    int rem = i & 63;
    int d0 = (rem >> 5) * 64, s0 = (rem & 31) * 64;
    const int t = threadIdx.x;
#pragma unroll
    for (int i2 = 0; i2 < 4; ++i2) {
      int s = i2 * 16 + (t >> 4), dd = (t & 15) * 4;
      h16x4 v = *(const h16x4*)(qkv + (size_t)(s0 + s) * QKVD + 5120 + kv * 128 + d0 + dd);
      *(h16x4*)&T[s * 66 + dd] = v;
    }
    __syncthreads();
#pragma unroll
    for (int i2 = 0; i2 < 4; ++i2) {
      int dr = i2 * 16 + (t >> 4), s4 = (t & 15) * 4;
      h16x4 o;
#pragma unroll
      for (int j = 0; j < 4; ++j) o[j] = T[(s4 + j) * 66 + dr];
      *(h16x4*)(vt + (size_t)kv * HD * SEQ + (size_t)(d0 + dr) * SEQ + s0 + s4) = o;
    }
  }
}

// ---------- flash attention: block = (h, qt), 128 q-rows, 4 waves x 32 rows, BK=64 ----------
__global__ __launch_bounds__(256, 3) void flash_attn(
    const h16* __restrict__ qkv, const h16* __restrict__ vt, h16* __restrict__ o_out) {
  __shared__ __attribute__((aligned(16))) h16 Ks[64 * 128];
  __shared__ __attribute__((aligned(16))) h16 Vts[128 * 64];
  __shared__ __attribute__((aligned(16))) h16 Ps[4][32 * 72];

  const int tid  = threadIdx.x;
  const int w    = tid >> 6, lane = tid & 63;
  const int quad = lane >> 4, l15 = lane & 15;
  const int h    = blockIdx.x;
  const int qt   = 15 - blockIdx.y;   // heavy tiles first
  const int kv   = h >> 2;
  const int rowq = qt * 128 + w * 32;
  const h16* vtg = vt + (size_t)kv * HD * SEQ;

  h16x8 qf[2][4];
#pragma unroll
  for (int mt = 0; mt < 2; ++mt) {
    const h16* qrow = qkv + (size_t)(rowq + mt * 16 + l15) * QKVD + h * 128;
#pragma unroll
    for (int ks = 0; ks < 4; ++ks)
      qf[mt][ks] = *(const h16x8*)(qrow + ks * 32 + quad * 8);
  }

  f32x4 o[2][8];
#pragma unroll
  for (int mt = 0; mt < 2; ++mt)
#pragma unroll
    for (int i = 0; i < 8; ++i) o[mt][i] = (f32x4){0.f, 0.f, 0.f, 0.f};
  float mrow[2][4], lrow[2][4];
#pragma unroll
  for (int mt = 0; mt < 2; ++mt)
#pragma unroll
    for (int r = 0; r < 4; ++r) { mrow[mt][r] = -3e30f; lrow[mt][r] = 0.f; }
  h16* Psw = Ps[w];

  const int nkt = 2 * qt + 2;
  for (int kt = 0; kt < nkt; ++kt) {
    const int k0 = kt * 64;
    __syncthreads();
#pragma unroll
    for (int i = 0; i < 4; ++i) {
      int c = i * 256 + tid;
      int key = c >> 4, d8s = c & 15;
      gload_lds16(qkv + (size_t)(k0 + key) * QKVD + 4096 + kv * 128 + (d8s ^ (key & 15)) * 8,
                  (char*)Ks + c * 16);
    }
#pragma unroll
    for (int i = 0; i < 4; ++i) {
      int c = i * 256 + tid;
      int d = c >> 3, p = c & 7;
      gload_lds16(vtg + (size_t)d * SEQ + k0 + (p ^ (d & 7)) * 8,
                  (char*)Vts + c * 16);
    }
    __syncthreads();

    if (k0 <= rowq + 31) {  // wave-uniform skip of fully-masked tiles
      const float sscale = 0.08838834764831845f;  // 1/sqrt(128)
      float alpha[2][4];
      f32x4 s2[2][4];
#pragma unroll
      for (int nt = 0; nt < 4; ++nt) {
        int key = nt * 16 + l15;
        f32x4 a0 = (f32x4){0.f, 0.f, 0.f, 0.f};
        f32x4 a1 = (f32x4){0.f, 0.f, 0.f, 0.f};
#pragma unroll
        for (int ks = 0; ks < 4; ++ks) {
          int d8 = ks * 4 + quad;
          h16x8 kf = *(const h16x8*)&Ks[key * 128 + ((d8 ^ (key & 15)) * 8)];
          a0 = __builtin_amdgcn_mfma_f32_16x16x32_f16(qf[0][ks], kf, a0, 0, 0, 0);
          a1 = __builtin_amdgcn_mfma_f32_16x16x32_f16(qf[1][ks], kf, a1, 0, 0, 0);
        }
        s2[0][nt] = a0;
        s2[1][nt] = a1;
      }
#pragma unroll
      for (int mt = 0; mt < 2; ++mt) {
#pragma unroll
        for (int r = 0; r < 4; ++r) {
          int rowg = rowq + mt * 16 + quad * 4 + r;
          float pv[4];
          float tm = -3e30f;
#pragma unroll
          for (int nt = 0; nt < 4; ++nt) {
            float v = s2[mt][nt][r] * sscale;
            if (k0 + nt * 16 + l15 > rowg) v = -3e30f;
            pv[nt] = v;
            tm = fmaxf(tm, v);
          }
          tm = red16_max(tm);                      // DPP, no LDS
          float mnew = fmaxf(mrow[mt][r], tm);
          float a = __expf(mrow[mt][r] - mnew);
          mrow[mt][r] = mnew;
          alpha[mt][r] = a;
          float ps = 0.f;
#pragma unroll
          for (int nt = 0; nt < 4; ++nt) {
            float e = __expf(pv[nt] - mnew);
            ps += e;
            Psw[(mt * 16 + quad * 4 + r) * 72 + nt * 16 + l15] = (h16)e;
          }
          ps = red16_sum(ps);                      // DPP, no LDS
          lrow[mt][r] = lrow[mt][r] * a + ps;
        }
      }
#pragma unroll
      for (int mt = 0; mt < 2; ++mt)
#pragma unroll
        for (int on = 0; on < 8; ++on) {
          o[mt][on][0] *= alpha[mt][0]; o[mt][on][1] *= alpha[mt][1];
          o[mt][on][2] *= alpha[mt][2]; o[mt][on][3] *= alpha[mt][3];
        }
      asm volatile("s_waitcnt lgkmcnt(0)" ::: "memory");
#pragma unroll
      for (int ks = 0; ks < 2; ++ks) {
        h16x8 pf0 = *(const h16x8*)&Psw[(0  + l15) * 72 + ks * 32 + quad * 8];
        h16x8 pf1 = *(const h16x8*)&Psw[(16 + l15) * 72 + ks * 32 + quad * 8];
        int k8 = ks * 4 + quad;
#pragma unroll
        for (int on = 0; on < 8; ++on) {
          int d = on * 16 + l15;
          h16x8 vf = *(const h16x8*)&Vts[d * 64 + ((k8 ^ (d & 7)) * 8)];
          o[0][on] = __builtin_amdgcn_mfma_f32_16x16x32_f16(pf0, vf, o[0][on], 0, 0, 0);
          o[1][on] = __builtin_amdgcn_mfma_f32_16x16x32_f16(pf1, vf, o[1][on], 0, 0, 0);
        }
      }
    }
  }
#pragma unroll
  for (int mt = 0; mt < 2; ++mt) {
    float linv[4];
#pragma unroll
    for (int r = 0; r < 4; ++r) linv[r] = 1.0f / lrow[mt][r];
#pragma unroll
    for (int on = 0; on < 8; ++on)
#pragma unroll
      for (int r = 0; r < 4; ++r) {
        int row = rowq + mt * 16 + quad * 4 + r;
        int col = h * 128 + on * 16 + l15;
        o_out[(size_t)row * DIMX + col] = (h16)(o[mt][on][r] * linv[r]);
      }
  }
}

extern "C" void kernel_launch(void* const* d_in, const int* in_sizes, int n_in,
                              void* d_out, int out_size, void* d_ws, size_t ws_size,
                              hipStream_t stream) {
  const float* x    = (const float*)d_in[0];
  const void*  wq   = d_in[1];
  const float* sq   = (const float*)d_in[2];
  const void*  wk   = d_in[3];
  const float* sk   = (const float*)d_in[4];
  const void*  wv   = d_in[5];
  const float* sv   = (const float*)d_in[6];
  const void*  wo   = d_in[7];
  const float* so   = (const float*)d_in[8];
  const float* cosb = (const float*)d_in[9];
  const float* sinb = (const float*)d_in[10];
  float* out = (float*)d_out;

  char* ws = (char*)d_ws;
  h16* Wqkv = (h16*)ws;                      // 6144*4096 h16 = 50331648 B
  h16* Wo   = (h16*)(ws + 50331648);         // 4096*4096 h16 = 33554432 B
  h16* xb   = (h16*)(ws + 83886080);         // 2048*4096 h16 (also attn_out later)
  h16* qkv  = (h16*)(ws + 100663296);        // 2048*6144 h16
  h16* vt   = (h16*)ws;                      // reuse Wqkv region after QKV GEMM (4 MB)

  // fused dequant (wq,wk,wv,wo) + cast(x): 7340032 units; flag computed in-kernel
  prep_all<<<28672, 256, 0, stream>>>(wq, sq, wk, sk, wv, sv, wo, so,
                                      (const float4*)x, Wqkv, Wo, (h16x4*)xb);

  // qkv = x @ Wqkv^T  (M=2048, N=6144, K=4096)
  gemm_bt<h16><<<dim3(48, 16), 256, 0, stream>>>(xb, Wqkv, qkv, SEQ, QKVD, DIMX);

  // RoPE (q,k) + V transpose into Vt[kv][d][s]  (Wqkv region dead after GEMM)
  rope_vtrans<<<5632, 256, 0, stream>>>(qkv, cosb, sinb, vt);

  // flash attention -> attn_out (reuse xb region)
  flash_attn<<<dim3(32, 16), 256, 0, stream>>>(qkv, vt, xb);

  // out = attn_out @ Wo^T  (M=2048, N=4096, K=4096), fp32 out
  gemm_bt<float><<<dim3(32, 16), 256, 0, stream>>>(xb, Wo, out, SEQ, DIMX, DIMX);
}

// Round 7
// 482.464 us; speedup vs baseline: 1.0841x; 1.0841x over previous
//
#include <hip/hip_runtime.h>
#include <stdint.h>

// Problem constants (fixed shapes)
#define DIMX 4096
#define NH   32
#define NKV  8
#define HD   128
#define SEQ  2048
#define QKVD 6144   // 4096 q + 1024 k + 1024 v

typedef _Float16 h16;
typedef __attribute__((ext_vector_type(8))) _Float16 h16x8;
typedef __attribute__((ext_vector_type(4))) _Float16 h16x4;
typedef __attribute__((ext_vector_type(4))) float   f32x4;

__device__ __forceinline__ void gload_lds16(const void* g, void* l) {
  __builtin_amdgcn_global_load_lds(
      (const __attribute__((address_space(1))) void*)g,
      (__attribute__((address_space(3))) void*)l, 16, 0, 0);
}

// ---- 16-lane reductions on the VALU via DPP reversal butterflies (no LDS pipe) ----
template <int CTRL>
__device__ __forceinline__ float dpp_mv(float x) {
  int y = __builtin_amdgcn_mov_dpp(__builtin_bit_cast(int, x), CTRL, 0xF, 0xF, true);
  return __builtin_bit_cast(float, y);
}
__device__ __forceinline__ float red16_max(float x) {
  x = fmaxf(x, dpp_mv<0xB1>(x));   // rev2: quad_perm(1,0,3,2)
  x = fmaxf(x, dpp_mv<0x1B>(x));   // rev4: quad_perm(3,2,1,0)
  x = fmaxf(x, dpp_mv<0x141>(x));  // rev8: row_half_mirror
  x = fmaxf(x, dpp_mv<0x140>(x));  // rev16: row_mirror
  return x;
}
__device__ __forceinline__ float red16_sum(float x) {
  x += dpp_mv<0xB1>(x);
  x += dpp_mv<0x1B>(x);
  x += dpp_mv<0x141>(x);
  x += dpp_mv<0x140>(x);
  return x;
}

// ---------- fused dequant (all 4 weights) + x cast, vectorized; flag computed per block ----------
__device__ __forceinline__ void dq_unit(const void* __restrict__ w, const float* __restrict__ sc,
                                        h16* __restrict__ out, int u, int flag) {
  uint32_t b4;
  if (flag) {
    const int4 t = *(const int4*)((const int*)w + 4 * u);
    b4 = (uint32_t)(t.x & 0xFF) | ((uint32_t)(t.y & 0xFF) << 8) |
         ((uint32_t)(t.z & 0xFF) << 16) | ((uint32_t)(t.w & 0xFF) << 24);
  } else {
    b4 = ((const uint32_t*)w)[u];
  }
  int r = u >> 4;
  int p = (u & 15) * 4;
  float shi = sc[2 * r], slo = sc[2 * r + 1];
  h16x4 hi, lo;
#pragma unroll
  for (int j = 0; j < 4; ++j) {
    int by = (int)((b4 >> (8 * j)) & 0xFF);
    int hn = (by << 24) >> 28;
    int ln = (by << 28) >> 28;
    hi[j] = (h16)((float)hn * shi);
    lo[j] = (h16)((float)ln * slo);
  }
  *(h16x4*)(out + (r << 7) + p)      = hi;
  *(h16x4*)(out + (r << 7) + 64 + p) = lo;
}

#define U_WQ 2097152
#define U_WK 524288
#define U_WV 524288
#define U_WO 2097152

__global__ __launch_bounds__(256) void prep_all(
    const void* __restrict__ wq, const float* __restrict__ sq,
    const void* __restrict__ wk, const float* __restrict__ sk,
    const void* __restrict__ wv, const float* __restrict__ sv,
    const void* __restrict__ wo, const float* __restrict__ so,
    const float4* __restrict__ x,
    h16* __restrict__ Wqkv, h16* __restrict__ Wo, h16x4* __restrict__ xb) {
  __shared__ int sfl;
  if (threadIdx.x == 0) {
    int ok = 1;
    const int* wi = (const int*)wq;
    for (int i = 0; i < 64; ++i) {
      int v = wi[i];
      if (v < -128 || v > 127) ok = 0;
    }
    sfl = ok;   // 1: ints were widened to int32; 0: raw int8 bytes
  }
  __syncthreads();
  const int fl = sfl;
  int u = blockIdx.x * 256 + threadIdx.x;
  if (u < U_WQ) { dq_unit(wq, sq, Wqkv, u, fl); return; }
  u -= U_WQ;
  if (u < U_WK) { dq_unit(wk, sk, Wqkv + 16777216, u, fl); return; }
  u -= U_WK;
  if (u < U_WV) { dq_unit(wv, sv, Wqkv + 20971520, u, fl); return; }
  u -= U_WV;
  if (u < U_WO) { dq_unit(wo, so, Wo, u, fl); return; }
  u -= U_WO;
  {
    float4 v = x[u];
    h16x4 o;
    o.x = (h16)v.x; o.y = (h16)v.y; o.z = (h16)v.z; o.w = (h16)v.w;
    xb[u] = o;
  }
}

// ---------- GEMM: C[M,N] = A[M,K] @ B[N,K]^T, fp16 in, OutT out ----------
// 128x128 tile, BK=64, XOR chunk swizzle (conflict-free b128 reads), 2-barrier K-loop.
template <typename OutT>
__global__ __launch_bounds__(256) void gemm_bt(
    const h16* __restrict__ A, const h16* __restrict__ B,
    OutT* __restrict__ C, int M, int N, int K) {
  __shared__ __attribute__((aligned(16))) h16 As[128 * 64];
  __shared__ __attribute__((aligned(16))) h16 Bs[128 * 64];
  const int tid  = threadIdx.x;
  const int wv   = tid >> 6, lane = tid & 63;
  const int wr   = wv >> 1,  wc   = wv & 1;
  const int quad = lane >> 4, l15 = lane & 15;
  const int m0 = blockIdx.y * 128, n0 = blockIdx.x * 128;

  f32x4 acc[4][4];
#pragma unroll
  for (int i = 0; i < 4; ++i)
#pragma unroll
    for (int j = 0; j < 4; ++j) acc[i][j] = (f32x4){0.f, 0.f, 0.f, 0.f};

  const h16* Ab = A + (size_t)m0 * K;
  const h16* Bb = B + (size_t)n0 * K;

  for (int k0 = 0; k0 < K; k0 += 64) {
    __syncthreads();
#pragma unroll
    for (int i = 0; i < 4; ++i) {
      int c = i * 256 + tid;           // 1024 slots per matrix
      int row = c >> 3, cs = c & 7;
      int g = cs ^ (row & 7);          // global chunk held at this slot
      gload_lds16(Ab + (size_t)row * K + k0 + g * 8, (char*)As + c * 16);
      gload_lds16(Bb + (size_t)row * K + k0 + g * 8, (char*)Bs + c * 16);
    }
    __syncthreads();

#pragma unroll
    for (int ks = 0; ks < 2; ++ks) {
      h16x8 af[4], bfr[4];
#pragma unroll
      for (int mt = 0; mt < 4; ++mt) {
        int row = wr * 64 + mt * 16 + l15;
        af[mt] = *(const h16x8*)&As[row * 64 + (((ks * 4 + quad) ^ (row & 7)) * 8)];
      }
#pragma unroll
      for (int nt = 0; nt < 4; ++nt) {
        int row = wc * 64 + nt * 16 + l15;
        bfr[nt] = *(const h16x8*)&Bs[row * 64 + (((ks * 4 + quad) ^ (row & 7)) * 8)];
      }
#pragma unroll
      for (int mt = 0; mt < 4; ++mt)
#pragma unroll
        for (int nt = 0; nt < 4; ++nt)
          acc[mt][nt] = __builtin_amdgcn_mfma_f32_16x16x32_f16(af[mt], bfr[nt], acc[mt][nt], 0, 0, 0);
    }
  }
#pragma unroll
  for (int mt = 0; mt < 4; ++mt)
#pragma unroll
    for (int nt = 0; nt < 4; ++nt)
#pragma unroll
      for (int r = 0; r < 4; ++r) {
        int row = m0 + wr * 64 + mt * 16 + quad * 4 + r;
        int col = n0 + wc * 64 + nt * 16 + l15;
        C[(size_t)row * N + col] = (OutT)acc[mt][nt][r];
      }
}

// ---------- fused RoPE (blocks 0..5119) + V transpose (blocks 5120..5631) ----------
__global__ __launch_bounds__(256) void rope_vtrans(
    h16* __restrict__ qkv, const float* __restrict__ cosb, const float* __restrict__ sinb,
    h16* __restrict__ vt) {
  __shared__ h16 T[64 * 66];
  int b = blockIdx.x;
  if (b < 5120) {
    int idx = b * 256 + threadIdx.x;
    int d4 = (idx & 15) * 4;
    int t  = idx >> 4;
    int hh = t % 40;
    int s  = t / 40;
    int base = (hh < 32) ? (s * QKVD + hh * 128)
                         : (s * QKVD + 4096 + (hh - 32) * 128);
    h16x4 a = *(const h16x4*)(qkv + base + d4);
    h16x4 bb = *(const h16x4*)(qkv + base + 64 + d4);
    float4 c  = *(const float4*)(cosb + s * 64 + d4);
    float4 sn = *(const float4*)(sinb + s * 64 + d4);
    h16x4 oa, ob;
    oa.x = (h16)((float)a.x * c.x - (float)bb.x * sn.x);
    oa.y = (h16)((float)a.y * c.y - (float)bb.y * sn.y);
    oa.z = (h16)((float)a.z * c.z - (float)bb.z * sn.z);
    oa.w = (h16)((float)a.w * c.w - (float)bb.w * sn.w);
    ob.x = (h16)((float)bb.x * c.x + (float)a.x * sn.x);
    ob.y = (h16)((float)bb.y * c.y + (float)a.y * sn.y);
    ob.z = (h16)((float)bb.z * c.z + (float)a.z * sn.z);
    ob.w = (h16)((float)bb.w * c.w + (float)a.w * sn.w);
    *(h16x4*)(qkv + base + d4)      = oa;
    *(h16x4*)(qkv + base + 64 + d4) = ob;
  } else {
    int i = b - 5120;                 // [0, 512)
    int kv = i >> 6;
    int rem = i & 63;
    int d0 = (rem >> 5) * 64, s0 = (rem & 31) * 64;
    const int t = threadIdx.x;
#pragma unroll
    for (int i2 = 0; i2 < 4; ++i2) {
      int s = i2 * 16 + (t >> 4), dd = (t & 15) * 4;
      h16x4 v = *(const h16x4*)(qkv + (size_t)(s0 + s) * QKVD + 5120 + kv * 128 + d0 + dd);
      *(h16x4*)&T[s * 66 + dd] = v;
    }
    __syncthreads();
#pragma unroll
    for (int i2 = 0; i2 < 4; ++i2) {
      int dr = i2 * 16 + (t >> 4), s4 = (t & 15) * 4;
      h16x4 o;
#pragma unroll
      for (int j = 0; j < 4; ++j) o[j] = T[(s4 + j) * 66 + dr];
      *(h16x4*)(vt + (size_t)kv * HD * SEQ + (size_t)(d0 + dr) * SEQ + s0 + s4) = o;
    }
  }
}

// ---------- flash attention: block = (h, y), 128 q-rows, 4 waves x 32 rows, BK=64 ----------
// qt mapping balances per-CU work: co-resident block pair (y, y+8) gets qt = 15-y and y,
// so every CU's two blocks sum to exactly 34 kt-steps (was 20..48).
__global__ __launch_bounds__(256, 2) void flash_attn(
    const h16* __restrict__ qkv, const h16* __restrict__ vt, h16* __restrict__ o_out) {
  __shared__ __attribute__((aligned(16))) h16 Ks[64 * 128];
  __shared__ __attribute__((aligned(16))) h16 Vts[128 * 64];
  __shared__ __attribute__((aligned(16))) h16 Ps[4][32 * 72];

  const int tid  = threadIdx.x;
  const int w    = tid >> 6, lane = tid & 63;
  const int quad = lane >> 4, l15 = lane & 15;
  const int h    = blockIdx.x;
  const int y    = blockIdx.y;
  const int qt   = (y < 8) ? (15 - y) : (y - 8);   // balanced heavy/light pairing
  const int kv   = h >> 2;
  const int rowq = qt * 128 + w * 32;
  const h16* vtg = vt + (size_t)kv * HD * SEQ;

  h16x8 qf[2][4];
#pragma unroll
  for (int mt = 0; mt < 2; ++mt) {
    const h16* qrow = qkv + (size_t)(rowq + mt * 16 + l15) * QKVD + h * 128;
#pragma unroll
    for (int ks = 0; ks < 4; ++ks)
      qf[mt][ks] = *(const h16x8*)(qrow + ks * 32 + quad * 8);
  }

  f32x4 o[2][8];
#pragma unroll
  for (int mt = 0; mt < 2; ++mt)
#pragma unroll
    for (int i = 0; i < 8; ++i) o[mt][i] = (f32x4){0.f, 0.f, 0.f, 0.f};
  float mrow[2][4], lrow[2][4];
#pragma unroll
  for (int mt = 0; mt < 2; ++mt)
#pragma unroll
    for (int r = 0; r < 4; ++r) { mrow[mt][r] = -3e30f; lrow[mt][r] = 0.f; }
  h16* Psw = Ps[w];

  const int nkt = 2 * qt + 2;
  for (int kt = 0; kt < nkt; ++kt) {
    const int k0 = kt * 64;
    __syncthreads();
#pragma unroll
    for (int i = 0; i < 4; ++i) {
      int c = i * 256 + tid;
      int key = c >> 4, d8s = c & 15;
      gload_lds16(qkv + (size_t)(k0 + key) * QKVD + 4096 + kv * 128 + (d8s ^ (key & 15)) * 8,
                  (char*)Ks + c * 16);
    }
#pragma unroll
    for (int i = 0; i < 4; ++i) {
      int c = i * 256 + tid;
      int d = c >> 3, p = c & 7;
      gload_lds16(vtg + (size_t)d * SEQ + k0 + (p ^ (d & 7)) * 8,
                  (char*)Vts + c * 16);
    }
    __syncthreads();

    if (k0 <= rowq + 31) {  // wave-uniform skip of fully-masked tiles
      const float sscale = 0.08838834764831845f;  // 1/sqrt(128)
      float alpha[2][4];
      f32x4 s2[2][4];
#pragma unroll
      for (int nt = 0; nt < 4; ++nt) {
        int key = nt * 16 + l15;
        f32x4 a0 = (f32x4){0.f, 0.f, 0.f, 0.f};
        f32x4 a1 = (f32x4){0.f, 0.f, 0.f, 0.f};
#pragma unroll
        for (int ks = 0; ks < 4; ++ks) {
          int d8 = ks * 4 + quad;
          h16x8 kf = *(const h16x8*)&Ks[key * 128 + ((d8 ^ (key & 15)) * 8)];
          a0 = __builtin_amdgcn_mfma_f32_16x16x32_f16(qf[0][ks], kf, a0, 0, 0, 0);
          a1 = __builtin_amdgcn_mfma_f32_16x16x32_f16(qf[1][ks], kf, a1, 0, 0, 0);
        }
        s2[0][nt] = a0;
        s2[1][nt] = a1;
      }
#pragma unroll
      for (int mt = 0; mt < 2; ++mt) {
#pragma unroll
        for (int r = 0; r < 4; ++r) {
          int rowg = rowq + mt * 16 + quad * 4 + r;
          float pv[4];
          float tm = -3e30f;
#pragma unroll
          for (int nt = 0; nt < 4; ++nt) {
            float v = s2[mt][nt][r] * sscale;
            if (k0 + nt * 16 + l15 > rowg) v = -3e30f;
            pv[nt] = v;
            tm = fmaxf(tm, v);
          }
          tm = red16_max(tm);                      // DPP, no LDS
          float mnew = fmaxf(mrow[mt][r], tm);
          float a = __expf(mrow[mt][r] - mnew);
          mrow[mt][r] = mnew;
          alpha[mt][r] = a;
          float ps = 0.f;
#pragma unroll
          for (int nt = 0; nt < 4; ++nt) {
            float e = __expf(pv[nt] - mnew);
            ps += e;
            Psw[(mt * 16 + quad * 4 + r) * 72 + nt * 16 + l15] = (h16)e;
          }
          ps = red16_sum(ps);                      // DPP, no LDS
          lrow[mt][r] = lrow[mt][r] * a + ps;
        }
      }
#pragma unroll
      for (int mt = 0; mt < 2; ++mt)
#pragma unroll
        for (int on = 0; on < 8; ++on) {
          o[mt][on][0] *= alpha[mt][0]; o[mt][on][1] *= alpha[mt][1];
          o[mt][on][2] *= alpha[mt][2]; o[mt][on][3] *= alpha[mt][3];
        }
      asm volatile("s_waitcnt lgkmcnt(0)" ::: "memory");
#pragma unroll
      for (int ks = 0; ks < 2; ++ks) {
        h16x8 pf0 = *(const h16x8*)&Psw[(0  + l15) * 72 + ks * 32 + quad * 8];
        h16x8 pf1 = *(const h16x8*)&Psw[(16 + l15) * 72 + ks * 32 + quad * 8];
        int k8 = ks * 4 + quad;
#pragma unroll
        for (int on = 0; on < 8; ++on) {
          int d = on * 16 + l15;
          h16x8 vf = *(const h16x8*)&Vts[d * 64 + ((k8 ^ (d & 7)) * 8)];
          o[0][on] = __builtin_amdgcn_mfma_f32_16x16x32_f16(pf0, vf, o[0][on], 0, 0, 0);
          o[1][on] = __builtin_amdgcn_mfma_f32_16x16x32_f16(pf1, vf, o[1][on], 0, 0, 0);
        }
      }
    }
  }
#pragma unroll
  for (int mt = 0; mt < 2; ++mt) {
    float linv[4];
#pragma unroll
    for (int r = 0; r < 4; ++r) linv[r] = 1.0f / lrow[mt][r];
#pragma unroll
    for (int on = 0; on < 8; ++on)
#pragma unroll
      for (int r = 0; r < 4; ++r) {
        int row = rowq + mt * 16 + quad * 4 + r;
        int col = h * 128 + on * 16 + l15;
        o_out[(size_t)row * DIMX + col] = (h16)(o[mt][on][r] * linv[r]);
      }
  }
}

extern "C" void kernel_launch(void* const* d_in, const int* in_sizes, int n_in,
                              void* d_out, int out_size, void* d_ws, size_t ws_size,
                              hipStream_t stream) {
  const float* x    = (const float*)d_in[0];
  const void*  wq   = d_in[1];
  const float* sq   = (const float*)d_in[2];
  const void*  wk   = d_in[3];
  const float* sk   = (const float*)d_in[4];
  const void*  wv   = d_in[5];
  const float* sv   = (const float*)d_in[6];
  const void*  wo   = d_in[7];
  const float* so   = (const float*)d_in[8];
  const float* cosb = (const float*)d_in[9];
  const float* sinb = (const float*)d_in[10];
  float* out = (float*)d_out;

  char* ws = (char*)d_ws;
  h16* Wqkv = (h16*)ws;                      // 6144*4096 h16 = 50331648 B
  h16* Wo   = (h16*)(ws + 50331648);         // 4096*4096 h16 = 33554432 B
  h16* xb   = (h16*)(ws + 83886080);         // 2048*4096 h16 (also attn_out later)
  h16* qkv  = (h16*)(ws + 100663296);        // 2048*6144 h16
  h16* vt   = (h16*)ws;                      // reuse Wqkv region after QKV GEMM (4 MB)

  // fused dequant (wq,wk,wv,wo) + cast(x): 7340032 units; flag computed in-kernel
  prep_all<<<28672, 256, 0, stream>>>(wq, sq, wk, sk, wv, sv, wo, so,
                                      (const float4*)x, Wqkv, Wo, (h16x4*)xb);

  // qkv = x @ Wqkv^T  (M=2048, N=6144, K=4096)
  gemm_bt<h16><<<dim3(48, 16), 256, 0, stream>>>(xb, Wqkv, qkv, SEQ, QKVD, DIMX);

  // RoPE (q,k) + V transpose into Vt[kv][d][s]  (Wqkv region dead after GEMM)
  rope_vtrans<<<5632, 256, 0, stream>>>(qkv, cosb, sinb, vt);

  // flash attention -> attn_out (reuse xb region)
  flash_attn<<<dim3(32, 16), 256, 0, stream>>>(qkv, vt, xb);

  // out = attn_out @ Wo^T  (M=2048, N=4096, K=4096), fp32 out
  gemm_bt<float><<<dim3(32, 16), 256, 0, stream>>>(xb, Wo, out, SEQ, DIMX, DIMX);
}

// Round 8
// 471.661 us; speedup vs baseline: 1.1090x; 1.0229x over previous
//
#include <hip/hip_runtime.h>
#include <stdint.h>

// Problem constants (fixed shapes)
#define DIMX 4096
#define NH   32
#define NKV  8
#define HD   128
#define SEQ  2048
#define QKVD 6144   // 4096 q + 1024 k + 1024 v

typedef _Float16 h16;
typedef __attribute__((ext_vector_type(8))) _Float16 h16x8;
typedef __attribute__((ext_vector_type(4))) _Float16 h16x4;
typedef __attribute__((ext_vector_type(4))) float   f32x4;

__device__ __forceinline__ void gload_lds16(const void* g, void* l) {
  __builtin_amdgcn_global_load_lds(
      (const __attribute__((address_space(1))) void*)g,
      (__attribute__((address_space(3))) void*)l, 16, 0, 0);
}

// ---- 16-lane reductions on the VALU via DPP reversal butterflies (no LDS pipe) ----
template <int CTRL>
__device__ __forceinline__ float dpp_mv(float x) {
  int y = __builtin_amdgcn_mov_dpp(__builtin_bit_cast(int, x), CTRL, 0xF, 0xF, true);
  return __builtin_bit_cast(float, y);
}
__device__ __forceinline__ float red16_max(float x) {
  x = fmaxf(x, dpp_mv<0xB1>(x));   // rev2
  x = fmaxf(x, dpp_mv<0x1B>(x));   // rev4
  x = fmaxf(x, dpp_mv<0x141>(x));  // rev8
  x = fmaxf(x, dpp_mv<0x140>(x));  // rev16
  return x;
}
__device__ __forceinline__ float red16_sum(float x) {
  x += dpp_mv<0xB1>(x);
  x += dpp_mv<0x1B>(x);
  x += dpp_mv<0x141>(x);
  x += dpp_mv<0x140>(x);
  return x;
}

// ---------- fused dequant (all 4 weights) + x cast ----------
__device__ __forceinline__ void dq_unit(const void* __restrict__ w, const float* __restrict__ sc,
                                        h16* __restrict__ out, int u, int flag) {
  uint32_t b4;
  if (flag) {
    const int4 t = *(const int4*)((const int*)w + 4 * u);
    b4 = (uint32_t)(t.x & 0xFF) | ((uint32_t)(t.y & 0xFF) << 8) |
         ((uint32_t)(t.z & 0xFF) << 16) | ((uint32_t)(t.w & 0xFF) << 24);
  } else {
    b4 = ((const uint32_t*)w)[u];
  }
  int r = u >> 4;
  int p = (u & 15) * 4;
  float shi = sc[2 * r], slo = sc[2 * r + 1];
  h16x4 hi, lo;
#pragma unroll
  for (int j = 0; j < 4; ++j) {
    int by = (int)((b4 >> (8 * j)) & 0xFF);
    int hn = (by << 24) >> 28;
    int ln = (by << 28) >> 28;
    hi[j] = (h16)((float)hn * shi);
    lo[j] = (h16)((float)ln * slo);
  }
  *(h16x4*)(out + (r << 7) + p)      = hi;
  *(h16x4*)(out + (r << 7) + 64 + p) = lo;
}

#define U_WQ 2097152
#define U_WK 524288
#define U_WV 524288
#define U_WO 2097152

__global__ __launch_bounds__(256) void prep_all(
    const void* __restrict__ wq, const float* __restrict__ sq,
    const void* __restrict__ wk, const float* __restrict__ sk,
    const void* __restrict__ wv, const float* __restrict__ sv,
    const void* __restrict__ wo, const float* __restrict__ so,
    const float4* __restrict__ x,
    h16* __restrict__ Wqkv, h16* __restrict__ Wo, h16x4* __restrict__ xb) {
  __shared__ int sfl;
  if (threadIdx.x == 0) {
    int ok = 1;
    const int* wi = (const int*)wq;
    for (int i = 0; i < 64; ++i) {
      int v = wi[i];
      if (v < -128 || v > 127) ok = 0;
    }
    sfl = ok;
  }
  __syncthreads();
  const int fl = sfl;
  int u = blockIdx.x * 256 + threadIdx.x;
  if (u < U_WQ) { dq_unit(wq, sq, Wqkv, u, fl); return; }
  u -= U_WQ;
  if (u < U_WK) { dq_unit(wk, sk, Wqkv + 16777216, u, fl); return; }
  u -= U_WK;
  if (u < U_WV) { dq_unit(wv, sv, Wqkv + 20971520, u, fl); return; }
  u -= U_WV;
  if (u < U_WO) { dq_unit(wo, so, Wo, u, fl); return; }
  u -= U_WO;
  {
    float4 v = x[u];
    h16x4 o;
    o.x = (h16)v.x; o.y = (h16)v.y; o.z = (h16)v.z; o.w = (h16)v.w;
    xb[u] = o;
  }
}

// ---------- GEMM: C[M,N] = A[M,K] @ B[N,K]^T ----------
// 128 x (NT*32) tile, BK=64, XOR chunk swizzle (0 bank conflicts).
// MODE 0: plain store. MODE 1 (QKV): fused RoPE epilogue for q/k blocks (n0<5120),
// direct register V-transpose into vt[kv][d][s] for v blocks (n0>=5120).
template <typename OutT, int NT, int MODE>
__global__ __launch_bounds__(256) void gemm_bt(
    const h16* __restrict__ A, const h16* __restrict__ B,
    OutT* __restrict__ C, int M, int N, int K,
    const float* __restrict__ cosb, const float* __restrict__ sinb,
    h16* __restrict__ vt) {
  constexpr int BN = NT * 32;
  constexpr int SAB = 128 * 64 + BN * 64;                 // staging h16 count
  constexpr int SSZ = (MODE == 1 && 128 * 136 > SAB) ? 128 * 136 : SAB;
  __shared__ __attribute__((aligned(16))) h16 SMEM[SSZ];
  h16* As = SMEM;
  h16* Bs = SMEM + 128 * 64;
  h16* T  = SMEM;                                          // alias, used after K-loop

  const int tid  = threadIdx.x;
  const int wv   = tid >> 6, lane = tid & 63;
  const int wr   = wv >> 1,  wc   = wv & 1;
  const int quad = lane >> 4, l15 = lane & 15;
  const int m0 = blockIdx.y * 128, n0 = blockIdx.x * BN;

  f32x4 acc[4][NT];
#pragma unroll
  for (int i = 0; i < 4; ++i)
#pragma unroll
    for (int j = 0; j < NT; ++j) acc[i][j] = (f32x4){0.f, 0.f, 0.f, 0.f};

  const h16* Ab = A + (size_t)m0 * K;
  const h16* Bb = B + (size_t)n0 * K;

  for (int k0 = 0; k0 < K; k0 += 64) {
    __syncthreads();
#pragma unroll
    for (int i = 0; i < 4; ++i) {
      int c = i * 256 + tid;
      int row = c >> 3, cs = c & 7, g = cs ^ (row & 7);
      gload_lds16(Ab + (size_t)row * K + k0 + g * 8, (char*)As + c * 16);
    }
#pragma unroll
    for (int i = 0; i < NT; ++i) {
      int c = i * 256 + tid;
      int row = c >> 3, cs = c & 7, g = cs ^ (row & 7);
      gload_lds16(Bb + (size_t)row * K + k0 + g * 8, (char*)Bs + c * 16);
    }
    __syncthreads();

#pragma unroll
    for (int ks = 0; ks < 2; ++ks) {
      h16x8 af[4], bfr[NT];
#pragma unroll
      for (int mt = 0; mt < 4; ++mt) {
        int row = wr * 64 + mt * 16 + l15;
        af[mt] = *(const h16x8*)&As[row * 64 + (((ks * 4 + quad) ^ (row & 7)) * 8)];
      }
#pragma unroll
      for (int nt = 0; nt < NT; ++nt) {
        int row = wc * (NT * 16) + nt * 16 + l15;
        bfr[nt] = *(const h16x8*)&Bs[row * 64 + (((ks * 4 + quad) ^ (row & 7)) * 8)];
      }
#pragma unroll
      for (int mt = 0; mt < 4; ++mt)
#pragma unroll
        for (int nt = 0; nt < NT; ++nt)
          acc[mt][nt] = __builtin_amdgcn_mfma_f32_16x16x32_f16(af[mt], bfr[nt], acc[mt][nt], 0, 0, 0);
    }
  }

  if (MODE == 1) {
    if (n0 < 5120) {
      // q/k block: C tile -> LDS (stride 136) -> paired RoPE -> qkv store
      __syncthreads();   // last iter's ds_reads done before T overwrite
#pragma unroll
      for (int mt = 0; mt < 4; ++mt)
#pragma unroll
        for (int nt = 0; nt < NT; ++nt)
#pragma unroll
          for (int r = 0; r < 4; ++r)
            T[(wr * 64 + mt * 16 + quad * 4 + r) * 136 + wc * 64 + nt * 16 + l15] =
                (h16)acc[mt][nt][r];
      __syncthreads();
      const int row = tid >> 1, half = tid & 1;
      const size_t gs = (size_t)(m0 + row);
#pragma unroll
      for (int i = 0; i < 8; ++i) {
        int c0 = half * 32 + i * 4;            // d in [0,64)
        h16x4 a = *(const h16x4*)&T[row * 136 + c0];
        h16x4 b = *(const h16x4*)&T[row * 136 + c0 + 64];
        float4 cc = *(const float4*)(cosb + gs * 64 + c0);
        float4 ss = *(const float4*)(sinb + gs * 64 + c0);
        h16x4 oa, ob;
        oa.x = (h16)((float)a.x * cc.x - (float)b.x * ss.x);
        oa.y = (h16)((float)a.y * cc.y - (float)b.y * ss.y);
        oa.z = (h16)((float)a.z * cc.z - (float)b.z * ss.z);
        oa.w = (h16)((float)a.w * cc.w - (float)b.w * ss.w);
        ob.x = (h16)((float)b.x * cc.x + (float)a.x * ss.x);
        ob.y = (h16)((float)b.y * cc.y + (float)a.y * ss.y);
        ob.z = (h16)((float)b.z * cc.z + (float)a.z * ss.z);
        ob.w = (h16)((float)b.w * cc.w + (float)a.w * ss.w);
        *(h16x4*)((h16*)C + gs * N + n0 + c0)      = oa;
        *(h16x4*)((h16*)C + gs * N + n0 + c0 + 64) = ob;
      }
    } else {
      // v block: direct register transpose into vt[kv][d][s] (4 consecutive s per reg quad)
      const int kvh = (n0 - 5120) >> 7;
      h16* vbase = vt + (size_t)kvh * HD * SEQ;
#pragma unroll
      for (int mt = 0; mt < 4; ++mt)
#pragma unroll
        for (int nt = 0; nt < NT; ++nt) {
          int d = wc * 64 + nt * 16 + l15;
          int s = m0 + wr * 64 + mt * 16 + quad * 4;
          h16x4 vvv;
#pragma unroll
          for (int r = 0; r < 4; ++r) vvv[r] = (h16)acc[mt][nt][r];
          *(h16x4*)(vbase + (size_t)d * SEQ + s) = vvv;
        }
    }
    return;
  }

#pragma unroll
  for (int mt = 0; mt < 4; ++mt)
#pragma unroll
    for (int nt = 0; nt < NT; ++nt)
#pragma unroll
      for (int r = 0; r < 4; ++r) {
        int row = m0 + wr * 64 + mt * 16 + quad * 4 + r;
        int col = n0 + wc * (NT * 16) + nt * 16 + l15;
        C[(size_t)row * N + col] = (OutT)acc[mt][nt][r];
      }
}

// ---------- flash attention: block = (h, y), 128 q-rows, 4 waves x 32 rows, BK=64 ----------
__global__ __launch_bounds__(256, 2) void flash_attn(
    const h16* __restrict__ qkv, const h16* __restrict__ vt, h16* __restrict__ o_out) {
  __shared__ __attribute__((aligned(16))) h16 Ks[64 * 128];
  __shared__ __attribute__((aligned(16))) h16 Vts[128 * 64];
  __shared__ __attribute__((aligned(16))) h16 Ps[4][32 * 72];

  const int tid  = threadIdx.x;
  const int w    = tid >> 6, lane = tid & 63;
  const int quad = lane >> 4, l15 = lane & 15;
  const int h    = blockIdx.x;
  const int y    = blockIdx.y;
  const int qt   = (y < 8) ? (15 - y) : (y - 8);   // balanced heavy/light pairing
  const int kv   = h >> 2;
  const int rowq = qt * 128 + w * 32;
  const h16* vtg = vt + (size_t)kv * HD * SEQ;

  h16x8 qf[2][4];
#pragma unroll
  for (int mt = 0; mt < 2; ++mt) {
    const h16* qrow = qkv + (size_t)(rowq + mt * 16 + l15) * QKVD + h * 128;
#pragma unroll
    for (int ks = 0; ks < 4; ++ks)
      qf[mt][ks] = *(const h16x8*)(qrow + ks * 32 + quad * 8);
  }

  f32x4 o[2][8];
#pragma unroll
  for (int mt = 0; mt < 2; ++mt)
#pragma unroll
    for (int i = 0; i < 8; ++i) o[mt][i] = (f32x4){0.f, 0.f, 0.f, 0.f};
  float mrow[2][4], lrow[2][4];
#pragma unroll
  for (int mt = 0; mt < 2; ++mt)
#pragma unroll
    for (int r = 0; r < 4; ++r) { mrow[mt][r] = -3e30f; lrow[mt][r] = 0.f; }
  h16* Psw = Ps[w];

  const int nkt = 2 * qt + 2;
  for (int kt = 0; kt < nkt; ++kt) {
    const int k0 = kt * 64;
    __syncthreads();
#pragma unroll
    for (int i = 0; i < 4; ++i) {
      int c = i * 256 + tid;
      int key = c >> 4, d8s = c & 15;
      gload_lds16(qkv + (size_t)(k0 + key) * QKVD + 4096 + kv * 128 + (d8s ^ (key & 15)) * 8,
                  (char*)Ks + c * 16);
    }
#pragma unroll
    for (int i = 0; i < 4; ++i) {
      int c = i * 256 + tid;
      int d = c >> 3, p = c & 7;
      gload_lds16(vtg + (size_t)d * SEQ + k0 + (p ^ (d & 7)) * 8,
                  (char*)Vts + c * 16);
    }
    __syncthreads();

    if (k0 <= rowq + 31) {
      const float sscale = 0.08838834764831845f;
      float alpha[2][4];
      f32x4 s2[2][4];
#pragma unroll
      for (int nt = 0; nt < 4; ++nt) {
        int key = nt * 16 + l15;
        f32x4 a0 = (f32x4){0.f, 0.f, 0.f, 0.f};
        f32x4 a1 = (f32x4){0.f, 0.f, 0.f, 0.f};
#pragma unroll
        for (int ks = 0; ks < 4; ++ks) {
          int d8 = ks * 4 + quad;
          h16x8 kf = *(const h16x8*)&Ks[key * 128 + ((d8 ^ (key & 15)) * 8)];
          a0 = __builtin_amdgcn_mfma_f32_16x16x32_f16(qf[0][ks], kf, a0, 0, 0, 0);
          a1 = __builtin_amdgcn_mfma_f32_16x16x32_f16(qf[1][ks], kf, a1, 0, 0, 0);
        }
        s2[0][nt] = a0;
        s2[1][nt] = a1;
      }
#pragma unroll
      for (int mt = 0; mt < 2; ++mt) {
#pragma unroll
        for (int r = 0; r < 4; ++r) {
          int rowg = rowq + mt * 16 + quad * 4 + r;
          float pv[4];
          float tm = -3e30f;
#pragma unroll
          for (int nt = 0; nt < 4; ++nt) {
            float v = s2[mt][nt][r] * sscale;
            if (k0 + nt * 16 + l15 > rowg) v = -3e30f;
            pv[nt] = v;
            tm = fmaxf(tm, v);
          }
          tm = red16_max(tm);
          float mnew = fmaxf(mrow[mt][r], tm);
          float a = __expf(mrow[mt][r] - mnew);
          mrow[mt][r] = mnew;
          alpha[mt][r] = a;
          float ps = 0.f;
#pragma unroll
          for (int nt = 0; nt < 4; ++nt) {
            float e = __expf(pv[nt] - mnew);
            ps += e;
            Psw[(mt * 16 + quad * 4 + r) * 72 + nt * 16 + l15] = (h16)e;
          }
          ps = red16_sum(ps);
          lrow[mt][r] = lrow[mt][r] * a + ps;
        }
      }
#pragma unroll
      for (int mt = 0; mt < 2; ++mt)
#pragma unroll
        for (int on = 0; on < 8; ++on) {
          o[mt][on][0] *= alpha[mt][0]; o[mt][on][1] *= alpha[mt][1];
          o[mt][on][2] *= alpha[mt][2]; o[mt][on][3] *= alpha[mt][3];
        }
      asm volatile("s_waitcnt lgkmcnt(0)" ::: "memory");
#pragma unroll
      for (int ks = 0; ks < 2; ++ks) {
        h16x8 pf0 = *(const h16x8*)&Psw[(0  + l15) * 72 + ks * 32 + quad * 8];
        h16x8 pf1 = *(const h16x8*)&Psw[(16 + l15) * 72 + ks * 32 + quad * 8];
        int k8 = ks * 4 + quad;
#pragma unroll
        for (int on = 0; on < 8; ++on) {
          int d = on * 16 + l15;
          h16x8 vf = *(const h16x8*)&Vts[d * 64 + ((k8 ^ (d & 7)) * 8)];
          o[0][on] = __builtin_amdgcn_mfma_f32_16x16x32_f16(pf0, vf, o[0][on], 0, 0, 0);
          o[1][on] = __builtin_amdgcn_mfma_f32_16x16x32_f16(pf1, vf, o[1][on], 0, 0, 0);
        }
      }
    }
  }
#pragma unroll
  for (int mt = 0; mt < 2; ++mt) {
    float linv[4];
#pragma unroll
    for (int r = 0; r < 4; ++r) linv[r] = 1.0f / lrow[mt][r];
#pragma unroll
    for (int on = 0; on < 8; ++on)
#pragma unroll
      for (int r = 0; r < 4; ++r) {
        int row = rowq + mt * 16 + quad * 4 + r;
        int col = h * 128 + on * 16 + l15;
        o_out[(size_t)row * DIMX + col] = (h16)(o[mt][on][r] * linv[r]);
      }
  }
}

extern "C" void kernel_launch(void* const* d_in, const int* in_sizes, int n_in,
                              void* d_out, int out_size, void* d_ws, size_t ws_size,
                              hipStream_t stream) {
  const float* x    = (const float*)d_in[0];
  const void*  wq   = d_in[1];
  const float* sq   = (const float*)d_in[2];
  const void*  wk   = d_in[3];
  const float* sk   = (const float*)d_in[4];
  const void*  wv   = d_in[5];
  const float* sv   = (const float*)d_in[6];
  const void*  wo   = d_in[7];
  const float* so   = (const float*)d_in[8];
  const float* cosb = (const float*)d_in[9];
  const float* sinb = (const float*)d_in[10];
  float* out = (float*)d_out;

  char* ws = (char*)d_ws;
  h16* Wqkv = (h16*)ws;                      // 6144*4096 h16 = 50331648 B
  h16* Wo   = (h16*)(ws + 50331648);         // 4096*4096 h16 = 33554432 B
  h16* xb   = (h16*)(ws + 83886080);         // x as h16; later attn_out
  h16* qkv  = (h16*)(ws + 100663296);        // 2048*6144 h16
  h16* vt   = (h16*)d_out;                   // vt scratch lives in d_out (dead until O-proj)

  // fused dequant (wq,wk,wv,wo) + cast(x)
  prep_all<<<28672, 256, 0, stream>>>(wq, sq, wk, sk, wv, sv, wo, so,
                                      (const float4*)x, Wqkv, Wo, (h16x4*)xb);

  // qkv = x @ Wqkv^T with fused RoPE (q,k) + direct V-transpose into vt
  gemm_bt<h16, 4, 1><<<dim3(48, 16), 256, 0, stream>>>(
      xb, Wqkv, qkv, SEQ, QKVD, DIMX, cosb, sinb, vt);

  // flash attention -> attn_out (reuse xb region)
  flash_attn<<<dim3(32, 16), 256, 0, stream>>>(qkv, vt, xb);

  // out = attn_out @ Wo^T  (BN=64 tile -> 1024 blocks, 4/CU)
  gemm_bt<float, 2, 0><<<dim3(64, 16), 256, 0, stream>>>(
      xb, Wo, out, SEQ, DIMX, DIMX, cosb, sinb, vt);
}